// Round 1
// baseline (677.772 us; speedup 1.0000x reference)
//
#include <hip/hip_runtime.h>
#include <hip/hip_bf16.h>
#include <math.h>

// ---------------- Kernel 1: q = x @ Wq^T ----------------
// A = x (2048 x 512) row-major, B = Wq (4096 x 512) row-major, C = q (2048 x 4096)
__global__ __launch_bounds__(256) void k1_gemm(const float* __restrict__ A,
                                               const float* __restrict__ B,
                                               float* __restrict__ C) {
    __shared__ float As[16][64];
    __shared__ float Bs[16][64];
    int t  = threadIdx.x;
    int tx = t & 15, ty = t >> 4;
    int m0 = blockIdx.y * 64, n0 = blockIdx.x * 64;
    float acc[4][4] = {};
    int lr = t >> 2;            // 0..63
    int lc = (t & 3) << 2;      // 0,4,8,12
    for (int k0 = 0; k0 < 512; k0 += 16) {
        float4 av = *(const float4*)&A[(m0 + lr) * 512 + k0 + lc];
        float4 bv = *(const float4*)&B[(n0 + lr) * 512 + k0 + lc];
        As[lc + 0][lr] = av.x; As[lc + 1][lr] = av.y; As[lc + 2][lr] = av.z; As[lc + 3][lr] = av.w;
        Bs[lc + 0][lr] = bv.x; Bs[lc + 1][lr] = bv.y; Bs[lc + 2][lr] = bv.z; Bs[lc + 3][lr] = bv.w;
        __syncthreads();
#pragma unroll
        for (int kk = 0; kk < 16; ++kk) {
            float4 a4 = *(const float4*)&As[kk][ty * 4];
            float4 b4 = *(const float4*)&Bs[kk][tx * 4];
            float a[4] = {a4.x, a4.y, a4.z, a4.w};
            float b[4] = {b4.x, b4.y, b4.z, b4.w};
#pragma unroll
            for (int i = 0; i < 4; ++i)
#pragma unroll
                for (int j = 0; j < 4; ++j) acc[i][j] += a[i] * b[j];
        }
        __syncthreads();
    }
#pragma unroll
    for (int i = 0; i < 4; ++i) {
        int m = m0 + ty * 4 + i;
        float4 o; o.x = acc[i][0]; o.y = acc[i][1]; o.z = acc[i][2]; o.w = acc[i][3];
        *(float4*)&C[m * 4096 + n0 + tx * 4] = o;
    }
}

// ---------------- Kernel 2: sim + top16 + combine + top16 + softmax ----------------
// grid: 2(c) * 8(h) * 64(ntile of 16) = 1024 blocks, 256 threads.
#define NT 16
__global__ __launch_bounds__(256) void k2_scores(const float* __restrict__ q,
                                                 const float* __restrict__ keys,
                                                 int* __restrict__ widx,
                                                 float* __restrict__ wcoef) {
    int bid = blockIdx.x;
    int c  = bid & 1;
    int h  = (bid >> 1) & 7;
    int n0 = (bid >> 4) * NT;

    __shared__ float q_s[2][NT][256];   // 32 KB
    __shared__ float s_sc[2][NT][256];  // 32 KB
    __shared__ float sx_s[2][NT][16];
    __shared__ int   ix_s[2][NT][16];

    int t = threadIdx.x;
    // stage q tiles (coalesced float4)
    for (int v = t; v < 2 * NT * 64; v += 256) {
        int p = v >> 10; int rem = v & 1023;
        int n = rem >> 6; int dq = (rem & 63) << 2;
        float4 src = *(const float4*)&q[((p * 1024) + (n0 + n)) * 4096 + c * 2048 + h * 256 + dq];
        *(float4*)&q_s[p][n][dq] = src;
    }
    __syncthreads();

    // scores: thread t owns key k=t; keys row chunked into registers
    for (int p = 0; p < 2; ++p) {
        float acc[NT];
#pragma unroll
        for (int n = 0; n < NT; ++n) acc[n] = 0.f;
        const float* krow = &keys[(((h * 256) + t) * 2 + p) * 256];
        for (int ch = 0; ch < 8; ++ch) {
            float kr[32];
#pragma unroll
            for (int j = 0; j < 8; ++j) {
                float4 kv = *(const float4*)&krow[ch * 32 + j * 4];
                kr[j * 4 + 0] = kv.x; kr[j * 4 + 1] = kv.y; kr[j * 4 + 2] = kv.z; kr[j * 4 + 3] = kv.w;
            }
#pragma unroll
            for (int n = 0; n < NT; ++n) {
#pragma unroll
                for (int d = 0; d < 32; d += 4) {
                    float4 qv = *(const float4*)&q_s[p][n][ch * 32 + d];
                    acc[n] += kr[d] * qv.x + kr[d + 1] * qv.y + kr[d + 2] * qv.z + kr[d + 3] * qv.w;
                }
            }
        }
#pragma unroll
        for (int n = 0; n < NT; ++n) s_sc[p][n][t] = acc[n];
    }
    __syncthreads();

    int wv = t >> 6, ln = t & 63;

    // per (p,n) top-16 over 256 keys: 32 tasks, 8 per wave
    for (int task = wv * 8; task < wv * 8 + 8; ++task) {
        int p = task >> 4, n = task & 15;
        float v0 = s_sc[p][n][ln];
        float v1 = s_sc[p][n][ln + 64];
        float v2 = s_sc[p][n][ln + 128];
        float v3 = s_sc[p][n][ln + 192];
        for (int r = 0; r < 16; ++r) {
            float bv = v0; int bk = ln;
            if (v1 > bv) { bv = v1; bk = ln + 64; }
            if (v2 > bv) { bv = v2; bk = ln + 128; }
            if (v3 > bv) { bv = v3; bk = ln + 192; }
            for (int s = 1; s < 64; s <<= 1) {
                float ov = __shfl_xor(bv, s);
                int   ok = __shfl_xor(bk, s);
                if (ov > bv || (ov == bv && ok < bk)) { bv = ov; bk = ok; }
            }
            if (ln == 0) { sx_s[p][n][r] = bv; ix_s[p][n][r] = bk; }
            if ((bk & 63) == ln) {
                int slot = bk >> 6;
                if      (slot == 0) v0 = -INFINITY;
                else if (slot == 1) v1 = -INFINITY;
                else if (slot == 2) v2 = -INFINITY;
                else                v3 = -INFINITY;
            }
        }
    }
    __syncthreads();

    // combine 16x16, top-16, softmax: 16 n-tasks, 4 per wave
    for (int task = wv * 4; task < wv * 4 + 4; ++task) {
        int n = task;
        float c0, c1, c2, c3;
        {
            int tt = ln;        c0 = sx_s[0][n][tt >> 4] + sx_s[1][n][tt & 15];
            tt = ln + 64;       c1 = sx_s[0][n][tt >> 4] + sx_s[1][n][tt & 15];
            tt = ln + 128;      c2 = sx_s[0][n][tt >> 4] + sx_s[1][n][tt & 15];
            tt = ln + 192;      c3 = sx_s[0][n][tt >> 4] + sx_s[1][n][tt & 15];
        }
        float m0 = 0.f, sum_e = 0.f, my_e = 0.f;
        int my_i = 0;
        for (int r = 0; r < 16; ++r) {
            float bv = c0; int bt = ln;
            if (c1 > bv) { bv = c1; bt = ln + 64; }
            if (c2 > bv) { bv = c2; bt = ln + 128; }
            if (c3 > bv) { bv = c3; bt = ln + 192; }
            for (int s = 1; s < 64; s <<= 1) {
                float ov = __shfl_xor(bv, s);
                int   ot = __shfl_xor(bt, s);
                if (ov > bv || (ov == bv && ot < bt)) { bv = ov; bt = ot; }
            }
            if (r == 0) m0 = bv;
            float e = expf(bv - m0);
            sum_e += e;
            int i = bt >> 4, jj = bt & 15;
            int eidx = ix_s[0][n][i] * 256 + ix_s[1][n][jj];
            if (ln == r) { my_e = e; my_i = eidx; }
            if ((bt & 63) == ln) {
                int slot = bt >> 6;
                if      (slot == 0) c0 = -INFINITY;
                else if (slot == 1) c1 = -INFINITY;
                else if (slot == 2) c2 = -INFINITY;
                else                c3 = -INFINITY;
            }
        }
        if (ln < 16) {
            int ng  = n0 + n;
            int off = ((c * 1024 + ng) * 8 + h) * 16 + ln;
            wcoef[off] = my_e / sum_e;
            widx[off]  = my_i;
        }
    }
}

// ---------------- Kernel 3: gather experts, gelu, weighted mix ----------------
// one block per (c,n); 4 waves x 32 experts; x and output accum in registers
__global__ __launch_bounds__(256) void k3_experts(const float* __restrict__ x,
                                                  const float* __restrict__ w_down,
                                                  const float* __restrict__ w_up,
                                                  const int* __restrict__ widx,
                                                  const float* __restrict__ wcoef,
                                                  float* __restrict__ out) {
    int bid = blockIdx.x;
    int c = bid >> 10, n = bid & 1023;
    int t = threadIdx.x, wv = t >> 6, ln = t & 63;
    __shared__ float wacc[4][512];

    const float* xrow = &x[(c * 1024 + n) * 512];
    float xr[8], oacc[8];
    {
        float4 xa = *(const float4*)&xrow[ln * 8];
        float4 xb = *(const float4*)&xrow[ln * 8 + 4];
        xr[0] = xa.x; xr[1] = xa.y; xr[2] = xa.z; xr[3] = xa.w;
        xr[4] = xb.x; xr[5] = xb.y; xr[6] = xb.z; xr[7] = xb.w;
    }
#pragma unroll
    for (int j = 0; j < 8; ++j) oacc[j] = 0.f;

    const int base = (c * 1024 + n) * 128;  // 8 heads * 16 experts
    for (int e = wv * 32; e < wv * 32 + 32; ++e) {
        int   idx = widx[base + e];
        float wgt = wcoef[base + e];
        const float* dr = &w_down[(long)idx * 512 + ln * 8];
        float4 da = *(const float4*)&dr[0];
        float4 db = *(const float4*)&dr[4];
        float part = da.x * xr[0] + da.y * xr[1] + da.z * xr[2] + da.w * xr[3]
                   + db.x * xr[4] + db.y * xr[5] + db.z * xr[6] + db.w * xr[7];
        for (int s = 1; s < 64; s <<= 1) part += __shfl_xor(part, s);
        float hv = part;
        float coef = 0.5f * hv * (1.f + erff(hv * 0.70710678118654752f)) * wgt;
        const float* ur = &w_up[(long)idx * 512 + ln * 8];
        float4 ua = *(const float4*)&ur[0];
        float4 ub = *(const float4*)&ur[4];
        oacc[0] += coef * ua.x; oacc[1] += coef * ua.y; oacc[2] += coef * ua.z; oacc[3] += coef * ua.w;
        oacc[4] += coef * ub.x; oacc[5] += coef * ub.y; oacc[6] += coef * ub.z; oacc[7] += coef * ub.w;
    }
#pragma unroll
    for (int j = 0; j < 8; ++j) wacc[wv][ln * 8 + j] = oacc[j];
    __syncthreads();

    float* orow = &out[(c * 1024 + n) * 512];
    for (int d = t; d < 512; d += 256)
        orow[d] = wacc[0][d] + wacc[1][d] + wacc[2][d] + wacc[3][d];
}

extern "C" void kernel_launch(void* const* d_in, const int* in_sizes, int n_in,
                              void* d_out, int out_size, void* d_ws, size_t ws_size,
                              hipStream_t stream) {
    const float* x      = (const float*)d_in[0];
    const float* Wq     = (const float*)d_in[1];
    const float* keys   = (const float*)d_in[2];
    const float* w_down = (const float*)d_in[3];
    const float* w_up   = (const float*)d_in[4];
    float* out = (float*)d_out;

    char* ws = (char*)d_ws;
    float* q     = (float*)ws;                               // 2048*4096*4 = 32 MiB
    int*   widx  = (int*)(ws + 2048UL * 4096 * 4);           // 262144*4 = 1 MiB
    float* wcoef = (float*)(ws + 2048UL * 4096 * 4 + 262144UL * 4);

    k1_gemm<<<dim3(64, 32), 256, 0, stream>>>(x, Wq, q);
    k2_scores<<<1024, 256, 0, stream>>>(q, keys, widx, wcoef);
    k3_experts<<<2048, 256, 0, stream>>>(x, w_down, w_up, widx, wcoef, out);
}

// Round 2
// 608.070 us; speedup vs baseline: 1.1146x; 1.1146x over previous
//
#include <hip/hip_runtime.h>
#include <hip/hip_bf16.h>
#include <math.h>

// ---------------- Kernel 1: q = x @ Wq^T ----------------
// A = x (2048 x 512) row-major, B = Wq (4096 x 512) row-major, C = q (2048 x 4096)
// 128x128 tile, 8x8 acc per thread, K-step 16.
__global__ __launch_bounds__(256) void k1_gemm(const float* __restrict__ A,
                                               const float* __restrict__ B,
                                               float* __restrict__ C) {
    __shared__ float As[16][128];
    __shared__ float Bs[16][128];
    int t  = threadIdx.x;
    int tx = t & 15, ty = t >> 4;          // tx: n-dim, ty: m-dim
    int m0 = blockIdx.y * 128, n0 = blockIdx.x * 128;
    float acc[8][8] = {};
    for (int k0 = 0; k0 < 512; k0 += 16) {
        // stage: 128 rows x 16 k for A and B; 512 float4 each; 2 per thread each
#pragma unroll
        for (int i = 0; i < 2; ++i) {
            int u   = t * 2 + i;
            int row = u >> 2;
            int kc  = (u & 3) << 2;
            float4 av = *(const float4*)&A[(m0 + row) * 512 + k0 + kc];
            float4 bv = *(const float4*)&B[(n0 + row) * 512 + k0 + kc];
            As[kc + 0][row] = av.x; As[kc + 1][row] = av.y; As[kc + 2][row] = av.z; As[kc + 3][row] = av.w;
            Bs[kc + 0][row] = bv.x; Bs[kc + 1][row] = bv.y; Bs[kc + 2][row] = bv.z; Bs[kc + 3][row] = bv.w;
        }
        __syncthreads();
#pragma unroll
        for (int kk = 0; kk < 16; ++kk) {
            float4 a0 = *(const float4*)&As[kk][ty * 8];
            float4 a1 = *(const float4*)&As[kk][ty * 8 + 4];
            float4 b0 = *(const float4*)&Bs[kk][tx * 8];
            float4 b1 = *(const float4*)&Bs[kk][tx * 8 + 4];
            float a[8] = {a0.x, a0.y, a0.z, a0.w, a1.x, a1.y, a1.z, a1.w};
            float b[8] = {b0.x, b0.y, b0.z, b0.w, b1.x, b1.y, b1.z, b1.w};
#pragma unroll
            for (int i = 0; i < 8; ++i)
#pragma unroll
                for (int j = 0; j < 8; ++j) acc[i][j] += a[i] * b[j];
        }
        __syncthreads();
    }
#pragma unroll
    for (int i = 0; i < 8; ++i) {
        int m = m0 + ty * 8 + i;
        float4 o0; o0.x = acc[i][0]; o0.y = acc[i][1]; o0.z = acc[i][2]; o0.w = acc[i][3];
        float4 o1; o1.x = acc[i][4]; o1.y = acc[i][5]; o1.z = acc[i][6]; o1.w = acc[i][7];
        *(float4*)&C[m * 4096 + n0 + tx * 8]     = o0;
        *(float4*)&C[m * 4096 + n0 + tx * 8 + 4] = o1;
    }
}

// ---------------- Kernel 2: sim + top16 + combine + top16 + softmax ----------------
// grid: 2(c) * 8(h) * 64(ntile of 16) = 1024 blocks, 256 threads.
// wave wv: p = wv>>1 (sim index / key half / q batch row), nh = wv&1 (n sub-half).
// lane owns 4 contiguous key rows (ln*4..ln*4+3) read from global (L2-resident);
// q read from LDS via broadcast float4; scores accumulate in registers.
#define NT 16
__global__ __launch_bounds__(256) void k2_scores(const float* __restrict__ q,
                                                 const float* __restrict__ keys,
                                                 int* __restrict__ widx,
                                                 float* __restrict__ wcoef) {
    int bid = blockIdx.x;
    int c  = bid & 1;
    int h  = (bid >> 1) & 7;
    int n0 = (bid >> 4) * NT;

    __shared__ float q_s[2][NT][256];   // 32 KB
    __shared__ float sx_s[2][NT][16];
    __shared__ int   ix_s[2][NT][16];

    int t = threadIdx.x;
    // stage q tiles (coalesced float4): q[(p*1024 + n0+n)*4096 + c*2048 + h*256 + d]
    for (int v = t; v < 2 * NT * 64; v += 256) {
        int p = v >> 10; int rem = v & 1023;
        int n = rem >> 6; int dq = (rem & 63) << 2;
        float4 src = *(const float4*)&q[((p * 1024) + (n0 + n)) * 4096 + c * 2048 + h * 256 + dq];
        *(float4*)&q_s[p][n][dq] = src;
    }
    __syncthreads();

    int wv = t >> 6, ln = t & 63;
    int p  = wv >> 1;       // which sim (batch row of q, key half)
    int nh = wv & 1;        // n sub-half: rows nh*8 .. nh*8+7

    // ---- score phase: acc[n][j] = S[p][n0 + nh*8 + n][ln*4 + j] ----
    float acc[8][4];
#pragma unroll
    for (int n = 0; n < 8; ++n)
#pragma unroll
        for (int j = 0; j < 4; ++j) acc[n][j] = 0.f;

    // key row for key k, half p: keys[((h*256 + k)*2 + p)*256 + d]; stride between k = 512 floats
    const float* kb = &keys[(((h * 256) + ln * 4) * 2 + p) * 256];
#pragma unroll 4
    for (int d0 = 0; d0 < 256; d0 += 4) {
        float4 k0 = *(const float4*)&kb[0 * 512 + d0];
        float4 k1 = *(const float4*)&kb[1 * 512 + d0];
        float4 k2 = *(const float4*)&kb[2 * 512 + d0];
        float4 k3 = *(const float4*)&kb[3 * 512 + d0];
#pragma unroll
        for (int n = 0; n < 8; ++n) {
            float4 qv = *(const float4*)&q_s[p][nh * 8 + n][d0];  // broadcast read
            acc[n][0] += qv.x * k0.x + qv.y * k0.y + qv.z * k0.z + qv.w * k0.w;
            acc[n][1] += qv.x * k1.x + qv.y * k1.y + qv.z * k1.z + qv.w * k1.w;
            acc[n][2] += qv.x * k2.x + qv.y * k2.y + qv.z * k2.z + qv.w * k2.w;
            acc[n][3] += qv.x * k3.x + qv.y * k3.y + qv.z * k3.z + qv.w * k3.w;
        }
    }

    // ---- top-16 per (p, n) directly from registers ----
#pragma unroll
    for (int n = 0; n < 8; ++n) {
        for (int r = 0; r < 16; ++r) {
            float bv = acc[n][0]; int bk = ln * 4;
            if (acc[n][1] > bv) { bv = acc[n][1]; bk = ln * 4 + 1; }
            if (acc[n][2] > bv) { bv = acc[n][2]; bk = ln * 4 + 2; }
            if (acc[n][3] > bv) { bv = acc[n][3]; bk = ln * 4 + 3; }
            for (int s = 1; s < 64; s <<= 1) {
                float ov = __shfl_xor(bv, s);
                int   ok = __shfl_xor(bk, s);
                if (ov > bv || (ov == bv && ok < bk)) { bv = ov; bk = ok; }
            }
            if (ln == 0) { sx_s[p][nh * 8 + n][r] = bv; ix_s[p][nh * 8 + n][r] = bk; }
            if ((bk >> 2) == ln) {
                int j = bk & 3;
                if      (j == 0) acc[n][0] = -INFINITY;
                else if (j == 1) acc[n][1] = -INFINITY;
                else if (j == 2) acc[n][2] = -INFINITY;
                else             acc[n][3] = -INFINITY;
            }
        }
    }
    __syncthreads();

    // ---- combine 16x16, top-16, softmax: 16 n-tasks, 4 per wave ----
    for (int task = wv * 4; task < wv * 4 + 4; ++task) {
        int n = task;
        float c0, c1, c2, c3;
        {
            int tt = ln;        c0 = sx_s[0][n][tt >> 4] + sx_s[1][n][tt & 15];
            tt = ln + 64;       c1 = sx_s[0][n][tt >> 4] + sx_s[1][n][tt & 15];
            tt = ln + 128;      c2 = sx_s[0][n][tt >> 4] + sx_s[1][n][tt & 15];
            tt = ln + 192;      c3 = sx_s[0][n][tt >> 4] + sx_s[1][n][tt & 15];
        }
        float m0 = 0.f, sum_e = 0.f, my_e = 0.f;
        int my_i = 0;
        for (int r = 0; r < 16; ++r) {
            float bv = c0; int bt = ln;
            if (c1 > bv) { bv = c1; bt = ln + 64; }
            if (c2 > bv) { bv = c2; bt = ln + 128; }
            if (c3 > bv) { bv = c3; bt = ln + 192; }
            for (int s = 1; s < 64; s <<= 1) {
                float ov = __shfl_xor(bv, s);
                int   ot = __shfl_xor(bt, s);
                if (ov > bv || (ov == bv && ot < bt)) { bv = ov; bt = ot; }
            }
            if (r == 0) m0 = bv;
            float e = expf(bv - m0);
            sum_e += e;
            int i = bt >> 4, jj = bt & 15;
            int eidx = ix_s[0][n][i] * 256 + ix_s[1][n][jj];
            if (ln == r) { my_e = e; my_i = eidx; }
            if ((bt & 63) == ln) {
                int slot = bt >> 6;
                if      (slot == 0) c0 = -INFINITY;
                else if (slot == 1) c1 = -INFINITY;
                else if (slot == 2) c2 = -INFINITY;
                else                c3 = -INFINITY;
            }
        }
        if (ln < 16) {
            int ng  = n0 + n;
            int off = ((c * 1024 + ng) * 8 + h) * 16 + ln;
            wcoef[off] = my_e / sum_e;
            widx[off]  = my_i;
        }
    }
}

// ---------------- Kernel 3: gather experts, gelu, weighted mix ----------------
// one block per (c,n); 4 waves x 32 experts; x and output accum in registers
__global__ __launch_bounds__(256) void k3_experts(const float* __restrict__ x,
                                                  const float* __restrict__ w_down,
                                                  const float* __restrict__ w_up,
                                                  const int* __restrict__ widx,
                                                  const float* __restrict__ wcoef,
                                                  float* __restrict__ out) {
    int bid = blockIdx.x;
    int c = bid >> 10, n = bid & 1023;
    int t = threadIdx.x, wv = t >> 6, ln = t & 63;
    __shared__ float wacc[4][512];

    const float* xrow = &x[(c * 1024 + n) * 512];
    float xr[8], oacc[8];
    {
        float4 xa = *(const float4*)&xrow[ln * 8];
        float4 xb = *(const float4*)&xrow[ln * 8 + 4];
        xr[0] = xa.x; xr[1] = xa.y; xr[2] = xa.z; xr[3] = xa.w;
        xr[4] = xb.x; xr[5] = xb.y; xr[6] = xb.z; xr[7] = xb.w;
    }
#pragma unroll
    for (int j = 0; j < 8; ++j) oacc[j] = 0.f;

    const int base = (c * 1024 + n) * 128;  // 8 heads * 16 experts
    for (int e = wv * 32; e < wv * 32 + 32; ++e) {
        int   idx = widx[base + e];
        float wgt = wcoef[base + e];
        const float* dr = &w_down[(long)idx * 512 + ln * 8];
        float4 da = *(const float4*)&dr[0];
        float4 db = *(const float4*)&dr[4];
        float part = da.x * xr[0] + da.y * xr[1] + da.z * xr[2] + da.w * xr[3]
                   + db.x * xr[4] + db.y * xr[5] + db.z * xr[6] + db.w * xr[7];
        for (int s = 1; s < 64; s <<= 1) part += __shfl_xor(part, s);
        float hv = part;
        float coef = 0.5f * hv * (1.f + erff(hv * 0.70710678118654752f)) * wgt;
        const float* ur = &w_up[(long)idx * 512 + ln * 8];
        float4 ua = *(const float4*)&ur[0];
        float4 ub = *(const float4*)&ur[4];
        oacc[0] += coef * ua.x; oacc[1] += coef * ua.y; oacc[2] += coef * ua.z; oacc[3] += coef * ua.w;
        oacc[4] += coef * ub.x; oacc[5] += coef * ub.y; oacc[6] += coef * ub.z; oacc[7] += coef * ub.w;
    }
#pragma unroll
    for (int j = 0; j < 8; ++j) wacc[wv][ln * 8 + j] = oacc[j];
    __syncthreads();

    float* orow = &out[(c * 1024 + n) * 512];
    for (int d = t; d < 512; d += 256)
        orow[d] = wacc[0][d] + wacc[1][d] + wacc[2][d] + wacc[3][d];
}

extern "C" void kernel_launch(void* const* d_in, const int* in_sizes, int n_in,
                              void* d_out, int out_size, void* d_ws, size_t ws_size,
                              hipStream_t stream) {
    const float* x      = (const float*)d_in[0];
    const float* Wq     = (const float*)d_in[1];
    const float* keys   = (const float*)d_in[2];
    const float* w_down = (const float*)d_in[3];
    const float* w_up   = (const float*)d_in[4];
    float* out = (float*)d_out;

    char* ws = (char*)d_ws;
    float* q     = (float*)ws;                               // 2048*4096*4 = 32 MiB
    int*   widx  = (int*)(ws + 2048UL * 4096 * 4);           // 262144*4 = 1 MiB
    float* wcoef = (float*)(ws + 2048UL * 4096 * 4 + 262144UL * 4);

    k1_gemm<<<dim3(32, 16), 256, 0, stream>>>(x, Wq, q);
    k2_scores<<<1024, 256, 0, stream>>>(q, keys, widx, wcoef);
    k3_experts<<<2048, 256, 0, stream>>>(x, w_down, w_up, widx, wcoef, out);
}